// Round 7
// baseline (246.922 us; speedup 1.0000x reference)
//
#include <hip/hip_runtime.h>
#include <hip/hip_bf16.h>
#include <math.h>

#define S_LEN 4096
#define DMODEL 768
#define NH 12
#define HD 64

using f32x4 = __attribute__((ext_vector_type(4))) float;
using s16x8 = __attribute__((ext_vector_type(8))) short;

__device__ inline ushort f2bf(float f) {
  union { float f; uint32_t u; } v; v.f = f;
  uint32_t r = v.u + 0x7fffu + ((v.u >> 16) & 1u);   // RTNE
  return (ushort)(r >> 16);
}
__device__ inline float bf2f(ushort u) {
  union { uint32_t u; float f; } v; v.u = ((uint32_t)u) << 16;
  return v.f;
}

__device__ __forceinline__ void gload16(const ushort* g, ushort* l) {
  __builtin_amdgcn_global_load_lds(
      (const __attribute__((address_space(1))) unsigned int*)g,
      (__attribute__((address_space(3))) unsigned int*)l, 16, 0, 0);
}

// scale folded into q: 1/sqrt(64) * log2(e)  -> softmax uses exp2
#define QSCL 0.18033688011112042f
#define DEFER_THR 8.0f

// ---------------- RoPE trig table (double precision on device) ----------------
__global__ void k_build_trig(float* __restrict__ ct, float* __restrict__ st) {
  const int s = blockIdx.x;
  const int d = threadIdx.x;
  const int j = d & 31;
  const double inv = pow(10000.0, -(double)j / 32.0);
  const double a = (double)s * inv;
  ct[s * HD + d] = (float)cos(a);
  st[s * HD + d] = (float)sin(a);
}

// ---------------- elementwise fp32 -> bf16 hi/lo split ----------------------
__global__ __launch_bounds__(256) void k_splitf(
    const float* __restrict__ in, ushort* __restrict__ oh,
    ushort* __restrict__ ol, int n4) {
  const int i = blockIdx.x * 256 + threadIdx.x;
  if (i >= n4) return;
  const float4 v = ((const float4*)in)[i];
  ushort4 h, lo;
  h.x = f2bf(v.x); lo.x = f2bf(v.x - bf2f(h.x));
  h.y = f2bf(v.y); lo.y = f2bf(v.y - bf2f(h.y));
  h.z = f2bf(v.z); lo.z = f2bf(v.z - bf2f(h.z));
  h.w = f2bf(v.w); lo.w = f2bf(v.w - bf2f(h.w));
  ((ushort4*)oh)[i] = h;
  ((ushort4*)ol)[i] = lo;
}

// ---------------- transpose + hi/lo bf16 split: W[R][C] -> T[C][R] ----------
__global__ __launch_bounds__(256) void k_tsplit(
    const float* __restrict__ W, ushort* __restrict__ Th,
    ushort* __restrict__ Tl, int R, int C) {
  __shared__ float tile[32][33];
  const int tx = threadIdx.x & 31, ty = threadIdx.x >> 5;  // 32 x 8
  const int c0 = blockIdx.x * 32, r0 = blockIdx.y * 32;
#pragma unroll
  for (int i = 0; i < 4; ++i)
    tile[ty + 8 * i][tx] = W[(size_t)(r0 + ty + 8 * i) * C + c0 + tx];
  __syncthreads();
#pragma unroll
  for (int i = 0; i < 4; ++i) {
    const float v = tile[tx][ty + 8 * i];
    const ushort h = f2bf(v);
    const size_t off = (size_t)(c0 + ty + 8 * i) * R + r0 + tx;
    Th[off] = h;
    Tl[off] = f2bf(v - bf2f(h));
  }
}

// ---------------- split-bf16 MFMA GEMM, BMx128 tile, BK=64 ------------------
// Staging via global_load_lds (16B), swizzle in the per-lane GLOBAL source.
// EPI 0 (BM=128): qkv epilogue (bias + RoPE; q hi/lo, k hi, V transposed)
// EPI 1: out epilogue (bias + fp32 store)
template <int EPI, int BM>
__global__ __launch_bounds__(256) void k_gemm_split(
    const ushort* __restrict__ Ah, const ushort* __restrict__ Al,
    const ushort* __restrict__ Bh, const ushort* __restrict__ Bl,
    const float* __restrict__ bias,
    const float* __restrict__ ct, const float* __restrict__ st,
    ushort* __restrict__ qh, ushort* __restrict__ ql,
    ushort* __restrict__ kh, ushort* __restrict__ vt,
    float* __restrict__ out) {
  constexpr int MF = BM / 32;                       // frags per wave in M
  // SS: Ah[BM*64] Al[BM*64] Bh[8192] Bl[8192]
  __shared__ __align__(16) ushort SS[2 * BM * 64 + 2 * 8192];

  const int t = threadIdx.x;
  const int w = t >> 6, l = t & 63, g = l >> 4, lq = l & 15;
  const int wm = w >> 1, wn = w & 1;
  const int m0 = blockIdx.y * BM, n0 = blockIdx.x * 128;

  f32x4 acc[MF][4];
#pragma unroll
  for (int i = 0; i < MF; ++i)
#pragma unroll
    for (int j = 0; j < 4; ++j) acc[i][j] = (f32x4){0.f, 0.f, 0.f, 0.f};

  // staging source: per-lane global addr with swizzle; LDS dest linear
  const ushort* gsrc;
  ushort* lbase;
  int ninst;
  if (w == 0)      { gsrc = Ah + (size_t)m0 * 768; lbase = SS;                 ninst = BM / 8; }
  else if (w == 1) { gsrc = Al + (size_t)m0 * 768; lbase = SS + BM * 64;       ninst = BM / 8; }
  else if (w == 2) { gsrc = Bh + (size_t)n0 * 768; lbase = SS + 2 * BM * 64;   ninst = 16; }
  else             { gsrc = Bl + (size_t)n0 * 768; lbase = SS + 2 * BM * 64 + 8192; ninst = 16; }
  const int grow = l >> 3, gch = l & 7;             // 8 rows x 8 chunks / inst
  gsrc += (size_t)grow * 768 + ((gch ^ grow) << 3);

  // fragment read bases
  const ushort* rdA[2], * rdB[2];
#pragma unroll
  for (int kk = 0; kk < 2; ++kk) {
    rdA[kk] = SS + wm * (BM / 2) * 64 + lq * 64 + ((((kk << 2) | g) ^ (lq & 7)) << 3);
    rdB[kk] = SS + 2 * BM * 64 + wn * 4096 + lq * 64 + ((((kk << 2) | g) ^ (lq & 7)) << 3);
  }

  for (int kt = 0; kt < 768 / 64; ++kt) {
    __syncthreads();
#pragma unroll
    for (int i = 0; i < 16; ++i)
      if (i < ninst) gload16(gsrc + (size_t)i * (8 * 768) + kt * 64, lbase + i * 512);
    __syncthreads();
#pragma unroll
    for (int kk = 0; kk < 2; ++kk) {
      s16x8 ah[MF], al4[MF];
#pragma unroll
      for (int mf = 0; mf < MF; ++mf) {
        ah[mf]  = *(const s16x8*)(rdA[kk] + mf * 1024);
        al4[mf] = *(const s16x8*)(rdA[kk] + mf * 1024 + BM * 64);
      }
      __builtin_amdgcn_s_setprio(1);
#pragma unroll
      for (int nf = 0; nf < 4; ++nf) {
        const s16x8 bhf = *(const s16x8*)(rdB[kk] + nf * 1024);
        const s16x8 blf = *(const s16x8*)(rdB[kk] + nf * 1024 + 8192);
#pragma unroll
        for (int mf = 0; mf < MF; ++mf) {
          acc[mf][nf] = __builtin_amdgcn_mfma_f32_16x16x32_bf16(ah[mf], bhf, acc[mf][nf], 0, 0, 0);
          acc[mf][nf] = __builtin_amdgcn_mfma_f32_16x16x32_bf16(ah[mf], blf, acc[mf][nf], 0, 0, 0);
          acc[mf][nf] = __builtin_amdgcn_mfma_f32_16x16x32_bf16(al4[mf], bhf, acc[mf][nf], 0, 0, 0);
        }
      }
      __builtin_amdgcn_s_setprio(0);
    }
  }

  if constexpr (EPI == 0) {
    const int cidx = n0 / DMODEL;   // 0:q 1:k 2:v (block-uniform)
    if (cidx < 2) {
      ushort* dh = (cidx == 0) ? qh : kh;
      const float scl = (cidx == 0) ? QSCL : 1.0f;
#pragma unroll
      for (int nf = 0; nf < 4; ++nf) {
        const int n = n0 + wn * 64 + nf * 16 + lq;
        const int rem = n - cidx * DMODEL;
        const int hh = rem >> 6, d = rem & 63;
        const float sgn = (d & 1) ? 1.f : -1.f;
        const float bb = bias[n];
#pragma unroll
        for (int mf = 0; mf < MF; ++mf)
#pragma unroll
          for (int rg = 0; rg < 4; ++rg) {
            const int s = m0 + wm * (BM / 2) + mf * 16 + g * 4 + rg;
            const float v = acc[mf][nf][rg] + bb;
            const float vp = __shfl_xor(v, 1, 64);
            const float o = (v * ct[s * HD + d] + sgn * vp * st[s * HD + d]) * scl;
            const ushort hv = f2bf(o);
            const size_t off = (((size_t)hh * S_LEN + s) << 6) + d;
            dh[off] = hv;
            if (cidx == 0) ql[off] = f2bf(o - bf2f(hv));
          }
      }
    } else {
#pragma unroll
      for (int nf = 0; nf < 4; ++nf) {
        const int n = n0 + wn * 64 + nf * 16 + lq;
        const int rem = n - 2 * DMODEL;
        const int hh = rem >> 6, d = rem & 63;
        const float bb = bias[n];
#pragma unroll
        for (int mf = 0; mf < MF; ++mf) {
          union { ushort us[4]; ushort4 u4; } u;
#pragma unroll
          for (int rg = 0; rg < 4; ++rg) u.us[rg] = f2bf(acc[mf][nf][rg] + bb);
          const int sb = m0 + wm * (BM / 2) + mf * 16 + g * 4;
          *(ushort4*)(vt + ((size_t)hh * 64 + d) * S_LEN + sb) = u.u4;
        }
      }
    }
  } else {
#pragma unroll
    for (int nf = 0; nf < 4; ++nf) {
      const int n = n0 + wn * 64 + nf * 16 + lq;
      const float bb = bias[n];
#pragma unroll
      for (int mf = 0; mf < MF; ++mf)
#pragma unroll
        for (int rg = 0; rg < 4; ++rg) {
          const int s = m0 + wm * (BM / 2) + mf * 16 + g * 4 + rg;
          out[(size_t)s * DMODEL + n] = acc[mf][nf][rg] + bb;
        }
    }
  }
}

// ---------------- flash attention: swapped QK^T, QBLK=128 -------------------
// grid (S/128, H), 256 threads = 4 waves; wave w owns 32 q-rows (2 groups).
// K/V tile reads are amortized over 2x q-rows vs QBLK=64.
__global__ __launch_bounds__(256) void k_attn_mfma(
    const ushort* __restrict__ qh, const ushort* __restrict__ ql,
    const ushort* __restrict__ kh, const ushort* __restrict__ vt,
    ushort* __restrict__ cxh, ushort* __restrict__ cxl) {
  const int h = blockIdx.y;
  const int s0 = blockIdx.x << 7;
  const int t = threadIdx.x;
  const int w = t >> 6, l = t & 63, lq = l & 15, g = l >> 4;

  __shared__ __align__(16) ushort Ks0[2 * 4096];  // [buf][64 k][64 d], swz
  __shared__ __align__(16) ushort Vs0[2 * 4096];  // [buf][64 d][64 k-perm], swz

  // Q B-fragments: u in {0,1} row-groups, hi/lo, two d-halves
  s16x8 qah[2][2], qal[2][2];
#pragma unroll
  for (int u = 0; u < 2; ++u) {
    const size_t qoff =
        ((size_t)h * S_LEN + s0 + (w << 5) + (u << 4) + lq) * 64 + (g << 3);
    qah[u][0] = *(const s16x8*)(qh + qoff);
    qah[u][1] = *(const s16x8*)(qh + qoff + 32);
    qal[u][0] = *(const s16x8*)(ql + qoff);
    qal[u][1] = *(const s16x8*)(ql + qoff + 32);
  }

  f32x4 o[2][4];
#pragma unroll
  for (int u = 0; u < 2; ++u)
#pragma unroll
    for (int m = 0; m < 4; ++m) o[u][m] = (f32x4){0.f, 0.f, 0.f, 0.f};
  float mrun[2] = {-3.0e30f, -3.0e30f};
  float lrun[2] = {0.f, 0.f};

  // loop-invariant LDS addresses
  const int b0 = (lq << 6) | ((g ^ (lq & 7)) << 3);
  const int b1 = (lq << 6) | (((g + 4) ^ (lq & 7)) << 3);
  const ushort* kr0 = Ks0 + b0;
  const ushort* kr1 = Ks0 + b1;
  const ushort* vr0 = Vs0 + b0;
  const ushort* vr1 = Vs0 + b1;
  const int r = t >> 2, c0 = (t & 3) << 1;
  const ushort* gk = kh + ((size_t)h * S_LEN + r) * 64 + (c0 << 3);
  const ushort* gv = vt + ((size_t)h * 64 + r) * S_LEN + (c0 << 3);
  ushort* kwp0 = Ks0 + ((r << 6) | ((c0 ^ (r & 7)) << 3));
  ushort* kwp1 = Ks0 + ((r << 6) | (((c0 + 1) ^ (r & 7)) << 3));
  ushort* vwp[2][2];
#pragma unroll
  for (int cc = 0; cc < 2; ++cc) {
    const int c = c0 + cc;
    const int k5 = c >> 2, k4 = (c >> 1) & 1, k3 = c & 1;
#pragma unroll
    for (int hh = 0; hh < 2; ++hh) {
      const int ch = 4 * k5 + 2 * k3 + hh;      // permuted chunk
      vwp[cc][hh] = Vs0 + ((r << 6) | ((ch ^ (r & 7)) << 3) | (k4 << 2));
    }
  }

  float4 sk0, sk1, sv0, sv1;
  sk0 = *(const float4*)(gk); sk1 = *(const float4*)(gk + 8);
  sv0 = *(const float4*)(gv); sv1 = *(const float4*)(gv + 8);
  gk += 4096; gv += 64;
  {
    *(float4*)(kwp0) = sk0;
    *(float4*)(kwp1) = sk1;
    union { float4 f; ushort4 h4[2]; } va, vb;
    va.f = sv0; vb.f = sv1;
    *(ushort4*)(vwp[0][0]) = va.h4[0];
    *(ushort4*)(vwp[0][1]) = va.h4[1];
    *(ushort4*)(vwp[1][0]) = vb.h4[0];
    *(ushort4*)(vwp[1][1]) = vb.h4[1];
  }
  __syncthreads();

  auto body = [&](const int CUR, const int NX, bool pref) {
    if (pref) {
      sk0 = *(const float4*)(gk); sk1 = *(const float4*)(gk + 8);
      sv0 = *(const float4*)(gv); sv1 = *(const float4*)(gv + 8);
      gk += 4096; gv += 64;
    }
    // ---- QK^T swapped, both row-groups share the K fragments ----
    f32x4 sc[2][4];
    __builtin_amdgcn_s_setprio(1);
#pragma unroll
    for (int n = 0; n < 4; ++n) {
      const s16x8 ka0 = *(const s16x8*)(kr0 + CUR * 4096 + (n << 10));
      const s16x8 ka1 = *(const s16x8*)(kr1 + CUR * 4096 + (n << 10));
#pragma unroll
      for (int u = 0; u < 2; ++u) {
        f32x4 a = {0.f, 0.f, 0.f, 0.f};
        a = __builtin_amdgcn_mfma_f32_16x16x32_bf16(ka0, qah[u][0], a, 0, 0, 0);
        a = __builtin_amdgcn_mfma_f32_16x16x32_bf16(ka1, qah[u][1], a, 0, 0, 0);
        a = __builtin_amdgcn_mfma_f32_16x16x32_bf16(ka0, qal[u][0], a, 0, 0, 0);
        a = __builtin_amdgcn_mfma_f32_16x16x32_bf16(ka1, qal[u][1], a, 0, 0, 0);
        sc[u][n] = a;
      }
    }
    __builtin_amdgcn_s_setprio(0);

    // ---- online softmax with defer-max (per row-group state) ----
    float pm[2];
#pragma unroll
    for (int u = 0; u < 2; ++u) {
      float p = sc[u][0][0];
#pragma unroll
      for (int n = 0; n < 4; ++n)
#pragma unroll
        for (int rg = 0; rg < 4; ++rg) p = fmaxf(p, sc[u][n][rg]);
      pm[u] = p;
    }
    if (!__all((pm[0] - mrun[0] <= DEFER_THR) &&
               (pm[1] - mrun[1] <= DEFER_THR))) {
#pragma unroll
      for (int u = 0; u < 2; ++u) {
        float p = pm[u];
        p = fmaxf(p, __shfl_xor(p, 16, 64));
        p = fmaxf(p, __shfl_xor(p, 32, 64));
        const float mn = fmaxf(mrun[u], p);
        const float corr = exp2f(mrun[u] - mn);
        mrun[u] = mn;
        lrun[u] *= corr;
#pragma unroll
        for (int m = 0; m < 4; ++m) o[u][m] *= corr;
      }
    }
    union Pf { uint32_t uw[4]; s16x8 v; };
    Pf pu[2][2];
#pragma unroll
    for (int u = 0; u < 2; ++u) {
      float pr[4][4];
      float rs = 0.f;
#pragma unroll
      for (int n = 0; n < 4; ++n)
#pragma unroll
        for (int rg = 0; rg < 4; ++rg) {
          pr[n][rg] = exp2f(sc[u][n][rg] - mrun[u]);
          rs += pr[n][rg];
        }
      lrun[u] += rs;
      uint32_t uu[8];
#pragma unroll
      for (int n = 0; n < 4; ++n) {
        asm("v_cvt_pk_bf16_f32 %0, %1, %2"
            : "=v"(uu[2 * n]) : "v"(pr[n][0]), "v"(pr[n][1]));
        asm("v_cvt_pk_bf16_f32 %0, %1, %2"
            : "=v"(uu[2 * n + 1]) : "v"(pr[n][2]), "v"(pr[n][3]));
      }
      pu[u][0].uw[0] = uu[0]; pu[u][0].uw[1] = uu[1];
      pu[u][0].uw[2] = uu[2]; pu[u][0].uw[3] = uu[3];
      pu[u][1].uw[0] = uu[4]; pu[u][1].uw[1] = uu[5];
      pu[u][1].uw[2] = uu[6]; pu[u][1].uw[3] = uu[7];
    }

    // ---- PV swapped, V fragments shared across row-groups ----
    __builtin_amdgcn_s_setprio(1);
#pragma unroll
    for (int m = 0; m < 4; ++m) {
      const s16x8 va0 = *(const s16x8*)(vr0 + CUR * 4096 + (m << 10));
      const s16x8 va1 = *(const s16x8*)(vr1 + CUR * 4096 + (m << 10));
#pragma unroll
      for (int u = 0; u < 2; ++u) {
        o[u][m] = __builtin_amdgcn_mfma_f32_16x16x32_bf16(va0, pu[u][0].v, o[u][m], 0, 0, 0);
        o[u][m] = __builtin_amdgcn_mfma_f32_16x16x32_bf16(va1, pu[u][1].v, o[u][m], 0, 0, 0);
      }
    }
    __builtin_amdgcn_s_setprio(0);

    if (pref) {
      *(float4*)(kwp0 + NX * 4096) = sk0;
      *(float4*)(kwp1 + NX * 4096) = sk1;
      union { float4 f; ushort4 h4[2]; } va, vb;
      va.f = sv0; vb.f = sv1;
      *(ushort4*)(vwp[0][0] + NX * 4096) = va.h4[0];
      *(ushort4*)(vwp[0][1] + NX * 4096) = va.h4[1];
      *(ushort4*)(vwp[1][0] + NX * 4096) = vb.h4[0];
      *(ushort4*)(vwp[1][1] + NX * 4096) = vb.h4[1];
    }
    __syncthreads();
  };

  for (int p = 0; p < 32; ++p) {
    body(0, 1, true);        // kt = 2p
    body(1, 0, p < 31);      // kt = 2p+1
  }

  // epilogue: finish deferred l-reduce, write ctx as bf16 hi/lo
#pragma unroll
  for (int u = 0; u < 2; ++u) {
    float lr = lrun[u];
    lr += __shfl_xor(lr, 16, 64);
    lr += __shfl_xor(lr, 32, 64);
    const float inv = 1.0f / lr;
    const size_t rowoff =
        (size_t)(s0 + (w << 5) + (u << 4) + lq) * DMODEL + (h << 6) + (g << 2);
    ushort* hrow = cxh + rowoff;
    ushort* lrow = cxl + rowoff;
#pragma unroll
    for (int m = 0; m < 4; ++m) {
      const float v0 = o[u][m][0] * inv, v1 = o[u][m][1] * inv;
      const float v2 = o[u][m][2] * inv, v3 = o[u][m][3] * inv;
      uint32_t h01, h23;
      asm("v_cvt_pk_bf16_f32 %0, %1, %2" : "=v"(h01) : "v"(v0), "v"(v1));
      asm("v_cvt_pk_bf16_f32 %0, %1, %2" : "=v"(h23) : "v"(v2), "v"(v3));
      const float r0 = __uint_as_float(h01 << 16);
      const float r1 = __uint_as_float(h01 & 0xffff0000u);
      const float r2 = __uint_as_float(h23 << 16);
      const float r3 = __uint_as_float(h23 & 0xffff0000u);
      uint32_t l01, l23;
      asm("v_cvt_pk_bf16_f32 %0, %1, %2" : "=v"(l01) : "v"(v0 - r0), "v"(v1 - r1));
      asm("v_cvt_pk_bf16_f32 %0, %1, %2" : "=v"(l23) : "v"(v2 - r2), "v"(v3 - r3));
      uint2 hq, lqv;
      hq.x = h01; hq.y = h23; lqv.x = l01; lqv.y = l23;
      *(uint2*)(hrow + (m << 4)) = hq;
      *(uint2*)(lrow + (m << 4)) = lqv;
    }
  }
}

extern "C" void kernel_launch(void* const* d_in, const int* in_sizes, int n_in,
                              void* d_out, int out_size, void* d_ws, size_t ws_size,
                              hipStream_t stream) {
  const float* x    = (const float*)d_in[0];
  const float* Wqkv = (const float*)d_in[1];
  const float* bqkv = (const float*)d_in[2];
  const float* Wout = (const float*)d_in[3];
  const float* bout = (const float*)d_in[4];
  float* out = (float*)d_out;

  const size_t NQ = (size_t)NH * S_LEN * HD;   // 3,145,728
  const size_t ND = (size_t)S_LEN * DMODEL;    // 3,145,728
  char* base = (char*)d_ws;
  ushort* qh = (ushort*)base;
  ushort* ql = qh + NQ;
  ushort* kh = ql + NQ;
  ushort* vt = kh + NQ;
  ushort* xh = vt + NQ;          // [S][768] hi; reused as cxh after qkv GEMM
  ushort* xl = xh + ND;          // lo; reused as cxl
  float* ct = (float*)(xl + ND);
  float* st = ct + (size_t)S_LEN * HD;
  ushort* Wth = (ushort*)(st + (size_t)S_LEN * HD);    // [2304][768]
  ushort* Wtl = Wth + (size_t)3 * DMODEL * DMODEL;
  ushort* Woth = Wtl + (size_t)3 * DMODEL * DMODEL;    // [768][768]
  ushort* Wotl = Woth + (size_t)DMODEL * DMODEL;

  k_build_trig<<<dim3(S_LEN), dim3(64), 0, stream>>>(ct, st);
  k_tsplit<<<dim3(3 * DMODEL / 32, DMODEL / 32), dim3(256), 0, stream>>>(
      Wqkv, Wth, Wtl, DMODEL, 3 * DMODEL);
  k_tsplit<<<dim3(DMODEL / 32, DMODEL / 32), dim3(256), 0, stream>>>(
      Wout, Woth, Wotl, DMODEL, DMODEL);
  k_splitf<<<dim3((int)(ND / 4 / 256)), dim3(256), 0, stream>>>(
      x, xh, xl, (int)(ND / 4));
  k_gemm_split<0, 128><<<dim3(3 * DMODEL / 128, S_LEN / 128), dim3(256), 0, stream>>>(
      xh, xl, Wth, Wtl, bqkv, ct, st, qh, ql, kh, vt, nullptr);
  k_attn_mfma<<<dim3(S_LEN / 128, NH), dim3(256), 0, stream>>>(
      qh, ql, kh, vt, xh, xl);
  k_gemm_split<1, 64><<<dim3(DMODEL / 128, S_LEN / 64), dim3(256), 0, stream>>>(
      xh, xl, Woth, Wotl, bout, nullptr, nullptr,
      nullptr, nullptr, nullptr, nullptr, out);
}

// Round 8
// 223.380 us; speedup vs baseline: 1.1054x; 1.1054x over previous
//
#include <hip/hip_runtime.h>
#include <hip/hip_bf16.h>
#include <math.h>

#define S_LEN 4096
#define DMODEL 768
#define NH 12
#define HD 64

using f32x4 = __attribute__((ext_vector_type(4))) float;
using s16x8 = __attribute__((ext_vector_type(8))) short;

__device__ inline ushort f2bf(float f) {
  union { float f; uint32_t u; } v; v.f = f;
  uint32_t r = v.u + 0x7fffu + ((v.u >> 16) & 1u);   // RTNE
  return (ushort)(r >> 16);
}
__device__ inline float bf2f(ushort u) {
  union { uint32_t u; float f; } v; v.u = ((uint32_t)u) << 16;
  return v.f;
}

__device__ __forceinline__ void gload16(const ushort* g, ushort* l) {
  __builtin_amdgcn_global_load_lds(
      (const __attribute__((address_space(1))) unsigned int*)g,
      (__attribute__((address_space(3))) unsigned int*)l, 16, 0, 0);
}

// scale folded into q: 1/sqrt(64) * log2(e)  -> softmax uses exp2
#define QSCL 0.18033688011112042f
#define DEFER_THR 8.0f

// ---------------- RoPE trig table (double precision on device) ----------------
__global__ void k_build_trig(float* __restrict__ ct, float* __restrict__ st) {
  const int s = blockIdx.x;
  const int d = threadIdx.x;
  const int j = d & 31;
  const double inv = pow(10000.0, -(double)j / 32.0);
  const double a = (double)s * inv;
  ct[s * HD + d] = (float)cos(a);
  st[s * HD + d] = (float)sin(a);
}

// ---------------- elementwise fp32 -> bf16 hi/lo split ----------------------
__global__ __launch_bounds__(256) void k_splitf(
    const float* __restrict__ in, ushort* __restrict__ oh,
    ushort* __restrict__ ol, int n4) {
  const int i = blockIdx.x * 256 + threadIdx.x;
  if (i >= n4) return;
  const float4 v = ((const float4*)in)[i];
  ushort4 h, lo;
  h.x = f2bf(v.x); lo.x = f2bf(v.x - bf2f(h.x));
  h.y = f2bf(v.y); lo.y = f2bf(v.y - bf2f(h.y));
  h.z = f2bf(v.z); lo.z = f2bf(v.z - bf2f(h.z));
  h.w = f2bf(v.w); lo.w = f2bf(v.w - bf2f(h.w));
  ((ushort4*)oh)[i] = h;
  ((ushort4*)ol)[i] = lo;
}

// ---------------- transpose + hi/lo bf16 split: W[R][C] -> T[C][R] ----------
__global__ __launch_bounds__(256) void k_tsplit(
    const float* __restrict__ W, ushort* __restrict__ Th,
    ushort* __restrict__ Tl, int R, int C) {
  __shared__ float tile[32][33];
  const int tx = threadIdx.x & 31, ty = threadIdx.x >> 5;  // 32 x 8
  const int c0 = blockIdx.x * 32, r0 = blockIdx.y * 32;
#pragma unroll
  for (int i = 0; i < 4; ++i)
    tile[ty + 8 * i][tx] = W[(size_t)(r0 + ty + 8 * i) * C + c0 + tx];
  __syncthreads();
#pragma unroll
  for (int i = 0; i < 4; ++i) {
    const float v = tile[tx][ty + 8 * i];
    const ushort h = f2bf(v);
    const size_t off = (size_t)(c0 + ty + 8 * i) * R + r0 + tx;
    Th[off] = h;
    Tl[off] = f2bf(v - bf2f(h));
  }
}

// ---------------- split-bf16 MFMA GEMM, BMx128 tile, BK=64 ------------------
template <int EPI, int BM>
__global__ __launch_bounds__(256) void k_gemm_split(
    const ushort* __restrict__ Ah, const ushort* __restrict__ Al,
    const ushort* __restrict__ Bh, const ushort* __restrict__ Bl,
    const float* __restrict__ bias,
    const float* __restrict__ ct, const float* __restrict__ st,
    ushort* __restrict__ qh, ushort* __restrict__ ql,
    ushort* __restrict__ kh, ushort* __restrict__ vt,
    float* __restrict__ out) {
  constexpr int MF = BM / 32;                       // frags per wave in M
  __shared__ __align__(16) ushort SS[2 * BM * 64 + 2 * 8192];

  const int t = threadIdx.x;
  const int w = t >> 6, l = t & 63, g = l >> 4, lq = l & 15;
  const int wm = w >> 1, wn = w & 1;
  const int m0 = blockIdx.y * BM, n0 = blockIdx.x * 128;

  f32x4 acc[MF][4];
#pragma unroll
  for (int i = 0; i < MF; ++i)
#pragma unroll
    for (int j = 0; j < 4; ++j) acc[i][j] = (f32x4){0.f, 0.f, 0.f, 0.f};

  const ushort* gsrc;
  ushort* lbase;
  int ninst;
  if (w == 0)      { gsrc = Ah + (size_t)m0 * 768; lbase = SS;                 ninst = BM / 8; }
  else if (w == 1) { gsrc = Al + (size_t)m0 * 768; lbase = SS + BM * 64;       ninst = BM / 8; }
  else if (w == 2) { gsrc = Bh + (size_t)n0 * 768; lbase = SS + 2 * BM * 64;   ninst = 16; }
  else             { gsrc = Bl + (size_t)n0 * 768; lbase = SS + 2 * BM * 64 + 8192; ninst = 16; }
  const int grow = l >> 3, gch = l & 7;
  gsrc += (size_t)grow * 768 + ((gch ^ grow) << 3);

  const ushort* rdA[2], * rdB[2];
#pragma unroll
  for (int kk = 0; kk < 2; ++kk) {
    rdA[kk] = SS + wm * (BM / 2) * 64 + lq * 64 + ((((kk << 2) | g) ^ (lq & 7)) << 3);
    rdB[kk] = SS + 2 * BM * 64 + wn * 4096 + lq * 64 + ((((kk << 2) | g) ^ (lq & 7)) << 3);
  }

  for (int kt = 0; kt < 768 / 64; ++kt) {
    __syncthreads();
#pragma unroll
    for (int i = 0; i < 16; ++i)
      if (i < ninst) gload16(gsrc + (size_t)i * (8 * 768) + kt * 64, lbase + i * 512);
    __syncthreads();
#pragma unroll
    for (int kk = 0; kk < 2; ++kk) {
      s16x8 ah[MF], al4[MF];
#pragma unroll
      for (int mf = 0; mf < MF; ++mf) {
        ah[mf]  = *(const s16x8*)(rdA[kk] + mf * 1024);
        al4[mf] = *(const s16x8*)(rdA[kk] + mf * 1024 + BM * 64);
      }
      __builtin_amdgcn_s_setprio(1);
#pragma unroll
      for (int nf = 0; nf < 4; ++nf) {
        const s16x8 bhf = *(const s16x8*)(rdB[kk] + nf * 1024);
        const s16x8 blf = *(const s16x8*)(rdB[kk] + nf * 1024 + 8192);
#pragma unroll
        for (int mf = 0; mf < MF; ++mf) {
          acc[mf][nf] = __builtin_amdgcn_mfma_f32_16x16x32_bf16(ah[mf], bhf, acc[mf][nf], 0, 0, 0);
          acc[mf][nf] = __builtin_amdgcn_mfma_f32_16x16x32_bf16(ah[mf], blf, acc[mf][nf], 0, 0, 0);
          acc[mf][nf] = __builtin_amdgcn_mfma_f32_16x16x32_bf16(al4[mf], bhf, acc[mf][nf], 0, 0, 0);
        }
      }
      __builtin_amdgcn_s_setprio(0);
    }
  }

  if constexpr (EPI == 0) {
    const int cidx = n0 / DMODEL;   // 0:q 1:k 2:v (block-uniform)
    if (cidx < 2) {
      ushort* dh = (cidx == 0) ? qh : kh;
      const float scl = (cidx == 0) ? QSCL : 1.0f;
#pragma unroll
      for (int nf = 0; nf < 4; ++nf) {
        const int n = n0 + wn * 64 + nf * 16 + lq;
        const int rem = n - cidx * DMODEL;
        const int hh = rem >> 6, d = rem & 63;
        const float sgn = (d & 1) ? 1.f : -1.f;
        const float bb = bias[n];
#pragma unroll
        for (int mf = 0; mf < MF; ++mf)
#pragma unroll
          for (int rg = 0; rg < 4; ++rg) {
            const int s = m0 + wm * (BM / 2) + mf * 16 + g * 4 + rg;
            const float v = acc[mf][nf][rg] + bb;
            const float vp = __shfl_xor(v, 1, 64);
            const float o = (v * ct[s * HD + d] + sgn * vp * st[s * HD + d]) * scl;
            const ushort hv = f2bf(o);
            const size_t off = (((size_t)hh * S_LEN + s) << 6) + d;
            dh[off] = hv;
            if (cidx == 0) ql[off] = f2bf(o - bf2f(hv));
          }
      }
    } else {
#pragma unroll
      for (int nf = 0; nf < 4; ++nf) {
        const int n = n0 + wn * 64 + nf * 16 + lq;
        const int rem = n - 2 * DMODEL;
        const int hh = rem >> 6, d = rem & 63;
        const float bb = bias[n];
#pragma unroll
        for (int mf = 0; mf < MF; ++mf) {
          union { ushort us[4]; ushort4 u4; } u;
#pragma unroll
          for (int rg = 0; rg < 4; ++rg) u.us[rg] = f2bf(acc[mf][nf][rg] + bb);
          const int sb = m0 + wm * (BM / 2) + mf * 16 + g * 4;
          *(ushort4*)(vt + ((size_t)hh * 64 + d) * S_LEN + sb) = u.u4;
        }
      }
    }
  } else {
#pragma unroll
    for (int nf = 0; nf < 4; ++nf) {
      const int n = n0 + wn * 64 + nf * 16 + lq;
      const float bb = bias[n];
#pragma unroll
      for (int mf = 0; mf < MF; ++mf)
#pragma unroll
        for (int rg = 0; rg < 4; ++rg) {
          const int s = m0 + wm * (BM / 2) + mf * 16 + g * 4 + rg;
          out[(size_t)s * DMODEL + n] = acc[mf][nf][rg] + bb;
        }
    }
  }
}

// ---------------- flash attention: swapped QK^T, 3-buf software pipeline -----
// grid (S/64, H), 256 threads = 4 waves; wave w owns q-rows s0+16w..+15.
// Per iter t: QK(t+1) MFMAs issue first (independent), softmax(t) runs on
// VALU/TRANS while MFMA+DS pipes drain, then PV(t). Stage tile t+2 -> LDS.
__global__ __launch_bounds__(256) void k_attn_mfma(
    const ushort* __restrict__ qh, const ushort* __restrict__ ql,
    const ushort* __restrict__ kh, const ushort* __restrict__ vt,
    ushort* __restrict__ cxh, ushort* __restrict__ cxl) {
  const int h = blockIdx.y;
  const int s0 = blockIdx.x << 6;
  const int t = threadIdx.x;
  const int w = t >> 6, l = t & 63, lq = l & 15, g = l >> 4;

  __shared__ __align__(16) ushort Ks0[3 * 4096];  // [buf][64 k][64 d], swz
  __shared__ __align__(16) ushort Vs0[3 * 4096];  // [buf][64 d][64 k-perm], swz

  s16x8 qa00, qa01, qa10, qa11;
  {
    const size_t qoff = ((size_t)h * S_LEN + s0 + (w << 4) + lq) * 64 + (g << 3);
    qa00 = *(const s16x8*)(qh + qoff);
    qa01 = *(const s16x8*)(qh + qoff + 32);
    qa10 = *(const s16x8*)(ql + qoff);
    qa11 = *(const s16x8*)(ql + qoff + 32);
  }

  f32x4 o[4];
#pragma unroll
  for (int m = 0; m < 4; ++m) o[m] = (f32x4){0.f, 0.f, 0.f, 0.f};
  float mrun = -3.0e30f, lrun = 0.f;

  // loop-invariant LDS addresses
  const int b0 = (lq << 6) | ((g ^ (lq & 7)) << 3);
  const int b1 = (lq << 6) | (((g + 4) ^ (lq & 7)) << 3);
  const ushort* kr0 = Ks0 + b0;
  const ushort* kr1 = Ks0 + b1;
  const ushort* vr0 = Vs0 + b0;
  const ushort* vr1 = Vs0 + b1;
  const int r = t >> 2, c0 = (t & 3) << 1;
  const ushort* gk = kh + ((size_t)h * S_LEN + r) * 64 + (c0 << 3);
  const ushort* gv = vt + ((size_t)h * 64 + r) * S_LEN + (c0 << 3);
  ushort* kwp0 = Ks0 + ((r << 6) | ((c0 ^ (r & 7)) << 3));
  ushort* kwp1 = Ks0 + ((r << 6) | (((c0 + 1) ^ (r & 7)) << 3));
  ushort* vwp[2][2];
#pragma unroll
  for (int cc = 0; cc < 2; ++cc) {
    const int c = c0 + cc;
    const int k5 = c >> 2, k4 = (c >> 1) & 1, k3 = c & 1;
#pragma unroll
    for (int hh = 0; hh < 2; ++hh) {
      const int ch = 4 * k5 + 2 * k3 + hh;      // permuted chunk
      vwp[cc][hh] = Vs0 + ((r << 6) | ((ch ^ (r & 7)) << 3) | (k4 << 2));
    }
  }

  float4 sk0, sk1, sv0, sv1;
  auto ldg = [&]() {
    sk0 = *(const float4*)(gk); sk1 = *(const float4*)(gk + 8);
    sv0 = *(const float4*)(gv); sv1 = *(const float4*)(gv + 8);
    gk += 4096; gv += 64;
  };
  auto ldsw = [&](const int B) {
    *(float4*)(kwp0 + B * 4096) = sk0;
    *(float4*)(kwp1 + B * 4096) = sk1;
    union { float4 f; ushort4 h4[2]; } va, vb;
    va.f = sv0; vb.f = sv1;
    *(ushort4*)(vwp[0][0] + B * 4096) = va.h4[0];
    *(ushort4*)(vwp[0][1] + B * 4096) = va.h4[1];
    *(ushort4*)(vwp[1][0] + B * 4096) = vb.h4[0];
    *(ushort4*)(vwp[1][1] + B * 4096) = vb.h4[1];
  };

  f32x4 scp[4];   // scores of tile t (pending softmax+PV)
  auto qk = [&](const int B, f32x4* sc) {
    __builtin_amdgcn_s_setprio(1);
#pragma unroll
    for (int n = 0; n < 4; ++n) {
      const s16x8 ka0 = *(const s16x8*)(kr0 + B * 4096 + (n << 10));
      const s16x8 ka1 = *(const s16x8*)(kr1 + B * 4096 + (n << 10));
      f32x4 a = {0.f, 0.f, 0.f, 0.f};
      a = __builtin_amdgcn_mfma_f32_16x16x32_bf16(ka0, qa00, a, 0, 0, 0);
      a = __builtin_amdgcn_mfma_f32_16x16x32_bf16(ka1, qa01, a, 0, 0, 0);
      a = __builtin_amdgcn_mfma_f32_16x16x32_bf16(ka0, qa10, a, 0, 0, 0);
      a = __builtin_amdgcn_mfma_f32_16x16x32_bf16(ka1, qa11, a, 0, 0, 0);
      sc[n] = a;
    }
    __builtin_amdgcn_s_setprio(0);
  };

  auto sm_pv = [&](const int B) {
    float pm = scp[0][0];
#pragma unroll
    for (int n = 0; n < 4; ++n)
#pragma unroll
      for (int rg = 0; rg < 4; ++rg) pm = fmaxf(pm, scp[n][rg]);
    if (!__all(pm - mrun <= DEFER_THR)) {
      pm = fmaxf(pm, __shfl_xor(pm, 16, 64));
      pm = fmaxf(pm, __shfl_xor(pm, 32, 64));
      const float mn = fmaxf(mrun, pm);
      const float corr = exp2f(mrun - mn);
      mrun = mn;
      lrun *= corr;
#pragma unroll
      for (int m = 0; m < 4; ++m) o[m] *= corr;
    }
    float pr[4][4];
    float rs = 0.f;
#pragma unroll
    for (int n = 0; n < 4; ++n)
#pragma unroll
      for (int rg = 0; rg < 4; ++rg) {
        pr[n][rg] = exp2f(scp[n][rg] - mrun);
        rs += pr[n][rg];
      }
    lrun += rs;
    uint32_t u[8];
#pragma unroll
    for (int n = 0; n < 4; ++n) {
      asm("v_cvt_pk_bf16_f32 %0, %1, %2"
          : "=v"(u[2 * n]) : "v"(pr[n][0]), "v"(pr[n][1]));
      asm("v_cvt_pk_bf16_f32 %0, %1, %2"
          : "=v"(u[2 * n + 1]) : "v"(pr[n][2]), "v"(pr[n][3]));
    }
    union { uint32_t uw[4]; s16x8 v; } p0, p1;
    p0.uw[0] = u[0]; p0.uw[1] = u[1]; p0.uw[2] = u[2]; p0.uw[3] = u[3];
    p1.uw[0] = u[4]; p1.uw[1] = u[5]; p1.uw[2] = u[6]; p1.uw[3] = u[7];
    __builtin_amdgcn_s_setprio(1);
#pragma unroll
    for (int m = 0; m < 4; ++m) {
      const s16x8 va0 = *(const s16x8*)(vr0 + B * 4096 + (m << 10));
      const s16x8 va1 = *(const s16x8*)(vr1 + B * 4096 + (m << 10));
      o[m] = __builtin_amdgcn_mfma_f32_16x16x32_bf16(va0, p0.v, o[m], 0, 0, 0);
      o[m] = __builtin_amdgcn_mfma_f32_16x16x32_bf16(va1, p1.v, o[m], 0, 0, 0);
    }
    __builtin_amdgcn_s_setprio(0);
  };

  // iteration t: QK from buf (t+1)%3, softmax+PV tile t from buf t%3,
  // stage tile t+2 into buf (t+2)%3
  auto iter = [&](const int QKB, const int PVB, const int WRB, const bool pref) {
    if (pref) ldg();
    f32x4 scc[4];
    qk(QKB, scc);
    sm_pv(PVB);
    if (pref) ldsw(WRB);
    __syncthreads();
    scp[0] = scc[0]; scp[1] = scc[1]; scp[2] = scc[2]; scp[3] = scc[3];
  };

  // prologue: buf0 <- tile0, buf1 <- tile1, scp = scores(tile0)
  ldg();
  ldsw(0);
  __syncthreads();
  ldg();
  qk(0, scp);
  ldsw(1);
  __syncthreads();

  for (int p = 0; p < 20; ++p) {
    iter(1, 0, 2, true);
    iter(2, 1, 0, true);
    iter(0, 2, 1, true);
  }
  iter(1, 0, 2, true);       // t=60
  iter(2, 1, 0, true);       // t=61 (stages tile 63 -> buf0)
  iter(0, 2, 1, false);      // t=62 (scp <- scores(tile 63))
  sm_pv(0);                  // tile 63

  // epilogue: finish deferred l-reduce, write ctx as bf16 hi/lo
  lrun += __shfl_xor(lrun, 16, 64);
  lrun += __shfl_xor(lrun, 32, 64);
  const float inv = 1.0f / lrun;
  const size_t rowoff = (size_t)(s0 + (w << 4) + lq) * DMODEL + (h << 6) + (g << 2);
  ushort* hrow = cxh + rowoff;
  ushort* lrow = cxl + rowoff;
#pragma unroll
  for (int m = 0; m < 4; ++m) {
    const float v0 = o[m][0] * inv, v1 = o[m][1] * inv;
    const float v2 = o[m][2] * inv, v3 = o[m][3] * inv;
    uint32_t h01, h23;
    asm("v_cvt_pk_bf16_f32 %0, %1, %2" : "=v"(h01) : "v"(v0), "v"(v1));
    asm("v_cvt_pk_bf16_f32 %0, %1, %2" : "=v"(h23) : "v"(v2), "v"(v3));
    const float r0 = __uint_as_float(h01 << 16);
    const float r1 = __uint_as_float(h01 & 0xffff0000u);
    const float r2 = __uint_as_float(h23 << 16);
    const float r3 = __uint_as_float(h23 & 0xffff0000u);
    uint32_t l01, l23;
    asm("v_cvt_pk_bf16_f32 %0, %1, %2" : "=v"(l01) : "v"(v0 - r0), "v"(v1 - r1));
    asm("v_cvt_pk_bf16_f32 %0, %1, %2" : "=v"(l23) : "v"(v2 - r2), "v"(v3 - r3));
    uint2 hq, lqv;
    hq.x = h01; hq.y = h23; lqv.x = l01; lqv.y = l23;
    *(uint2*)(hrow + (m << 4)) = hq;
    *(uint2*)(lrow + (m << 4)) = lqv;
  }
}

extern "C" void kernel_launch(void* const* d_in, const int* in_sizes, int n_in,
                              void* d_out, int out_size, void* d_ws, size_t ws_size,
                              hipStream_t stream) {
  const float* x    = (const float*)d_in[0];
  const float* Wqkv = (const float*)d_in[1];
  const float* bqkv = (const float*)d_in[2];
  const float* Wout = (const float*)d_in[3];
  const float* bout = (const float*)d_in[4];
  float* out = (float*)d_out;

  const size_t NQ = (size_t)NH * S_LEN * HD;   // 3,145,728
  const size_t ND = (size_t)S_LEN * DMODEL;    // 3,145,728
  char* base = (char*)d_ws;
  ushort* qh = (ushort*)base;
  ushort* ql = qh + NQ;
  ushort* kh = ql + NQ;
  ushort* vt = kh + NQ;
  ushort* xh = vt + NQ;          // [S][768] hi; reused as cxh after qkv GEMM
  ushort* xl = xh + ND;          // lo; reused as cxl
  float* ct = (float*)(xl + ND);
  float* st = ct + (size_t)S_LEN * HD;
  ushort* Wth = (ushort*)(st + (size_t)S_LEN * HD);    // [2304][768]
  ushort* Wtl = Wth + (size_t)3 * DMODEL * DMODEL;
  ushort* Woth = Wtl + (size_t)3 * DMODEL * DMODEL;    // [768][768]
  ushort* Wotl = Woth + (size_t)DMODEL * DMODEL;

  k_build_trig<<<dim3(S_LEN), dim3(64), 0, stream>>>(ct, st);
  k_tsplit<<<dim3(3 * DMODEL / 32, DMODEL / 32), dim3(256), 0, stream>>>(
      Wqkv, Wth, Wtl, DMODEL, 3 * DMODEL);
  k_tsplit<<<dim3(DMODEL / 32, DMODEL / 32), dim3(256), 0, stream>>>(
      Wout, Woth, Wotl, DMODEL, DMODEL);
  k_splitf<<<dim3((int)(ND / 4 / 256)), dim3(256), 0, stream>>>(
      x, xh, xl, (int)(ND / 4));
  k_gemm_split<0, 128><<<dim3(3 * DMODEL / 128, S_LEN / 128), dim3(256), 0, stream>>>(
      xh, xl, Wth, Wtl, bqkv, ct, st, qh, ql, kh, vt, nullptr);
  k_attn_mfma<<<dim3(S_LEN / 64, NH), dim3(256), 0, stream>>>(
      qh, ql, kh, vt, xh, xl);
  k_gemm_split<1, 64><<<dim3(DMODEL / 128, S_LEN / 64), dim3(256), 0, stream>>>(
      xh, xl, Woth, Wotl, bout, nullptr, nullptr,
      nullptr, nullptr, nullptr, nullptr, out);
}

// Round 9
// 222.404 us; speedup vs baseline: 1.1102x; 1.0044x over previous
//
#include <hip/hip_runtime.h>
#include <hip/hip_bf16.h>
#include <math.h>

#define S_LEN 4096
#define DMODEL 768
#define NH 12
#define HD 64

using f32x4 = __attribute__((ext_vector_type(4))) float;
using s16x8 = __attribute__((ext_vector_type(8))) short;

__device__ inline ushort f2bf(float f) {
  union { float f; uint32_t u; } v; v.f = f;
  uint32_t r = v.u + 0x7fffu + ((v.u >> 16) & 1u);   // RTNE
  return (ushort)(r >> 16);
}
__device__ inline float bf2f(ushort u) {
  union { uint32_t u; float f; } v; v.u = ((uint32_t)u) << 16;
  return v.f;
}

__device__ __forceinline__ void gload16(const ushort* g, ushort* l) {
  __builtin_amdgcn_global_load_lds(
      (const __attribute__((address_space(1))) unsigned int*)g,
      (__attribute__((address_space(3))) unsigned int*)l, 16, 0, 0);
}

// scale folded into q: 1/sqrt(64) * log2(e)  -> softmax uses exp2
#define QSCL 0.18033688011112042f
#define DEFER_THR 8.0f

// ---------------- RoPE trig table (double precision on device) ----------------
__global__ void k_build_trig(float* __restrict__ ct, float* __restrict__ st) {
  const int s = blockIdx.x;
  const int d = threadIdx.x;
  const int j = d & 31;
  const double inv = pow(10000.0, -(double)j / 32.0);
  const double a = (double)s * inv;
  ct[s * HD + d] = (float)cos(a);
  st[s * HD + d] = (float)sin(a);
}

// ---------------- elementwise fp32 -> bf16 hi/lo split ----------------------
__global__ __launch_bounds__(256) void k_splitf(
    const float* __restrict__ in, ushort* __restrict__ oh,
    ushort* __restrict__ ol, int n4) {
  const int i = blockIdx.x * 256 + threadIdx.x;
  if (i >= n4) return;
  const float4 v = ((const float4*)in)[i];
  ushort4 h, lo;
  h.x = f2bf(v.x); lo.x = f2bf(v.x - bf2f(h.x));
  h.y = f2bf(v.y); lo.y = f2bf(v.y - bf2f(h.y));
  h.z = f2bf(v.z); lo.z = f2bf(v.z - bf2f(h.z));
  h.w = f2bf(v.w); lo.w = f2bf(v.w - bf2f(h.w));
  ((ushort4*)oh)[i] = h;
  ((ushort4*)ol)[i] = lo;
}

// ---------------- transpose + hi/lo bf16 split: W[R][C] -> T[C][R] ----------
__global__ __launch_bounds__(256) void k_tsplit(
    const float* __restrict__ W, ushort* __restrict__ Th,
    ushort* __restrict__ Tl, int R, int C) {
  __shared__ float tile[32][33];
  const int tx = threadIdx.x & 31, ty = threadIdx.x >> 5;  // 32 x 8
  const int c0 = blockIdx.x * 32, r0 = blockIdx.y * 32;
#pragma unroll
  for (int i = 0; i < 4; ++i)
    tile[ty + 8 * i][tx] = W[(size_t)(r0 + ty + 8 * i) * C + c0 + tx];
  __syncthreads();
#pragma unroll
  for (int i = 0; i < 4; ++i) {
    const float v = tile[tx][ty + 8 * i];
    const ushort h = f2bf(v);
    const size_t off = (size_t)(c0 + ty + 8 * i) * R + r0 + tx;
    Th[off] = h;
    Tl[off] = f2bf(v - bf2f(h));
  }
}

// ---------------- split-bf16 MFMA GEMM, BMx128 tile, BK=64 ------------------
// XCD-aware block swizzle (grid%8==0): each XCD gets contiguous panel chunk.
template <int EPI, int BM>
__global__ __launch_bounds__(256) void k_gemm_split(
    const ushort* __restrict__ Ah, const ushort* __restrict__ Al,
    const ushort* __restrict__ Bh, const ushort* __restrict__ Bl,
    const float* __restrict__ bias,
    const float* __restrict__ ct, const float* __restrict__ st,
    ushort* __restrict__ qh, ushort* __restrict__ ql,
    ushort* __restrict__ kh, ushort* __restrict__ vt,
    float* __restrict__ out) {
  constexpr int MF = BM / 32;                       // frags per wave in M
  __shared__ __align__(16) ushort SS[2 * BM * 64 + 2 * 8192];

  const int t = threadIdx.x;
  const int w = t >> 6, l = t & 63, g = l >> 4, lq = l & 15;
  const int wm = w >> 1, wn = w & 1;
  const int nbx = gridDim.x;
  int lin = blockIdx.y * nbx + blockIdx.x;
  const int cpx = (nbx * gridDim.y) >> 3;
  lin = (lin & 7) * cpx + (lin >> 3);               // bijective (grid%8==0)
  const int m0 = (lin / nbx) * BM, n0 = (lin % nbx) * 128;

  f32x4 acc[MF][4];
#pragma unroll
  for (int i = 0; i < MF; ++i)
#pragma unroll
    for (int j = 0; j < 4; ++j) acc[i][j] = (f32x4){0.f, 0.f, 0.f, 0.f};

  const ushort* gsrc;
  ushort* lbase;
  int ninst;
  if (w == 0)      { gsrc = Ah + (size_t)m0 * 768; lbase = SS;                 ninst = BM / 8; }
  else if (w == 1) { gsrc = Al + (size_t)m0 * 768; lbase = SS + BM * 64;       ninst = BM / 8; }
  else if (w == 2) { gsrc = Bh + (size_t)n0 * 768; lbase = SS + 2 * BM * 64;   ninst = 16; }
  else             { gsrc = Bl + (size_t)n0 * 768; lbase = SS + 2 * BM * 64 + 8192; ninst = 16; }
  const int grow = l >> 3, gch = l & 7;
  gsrc += (size_t)grow * 768 + ((gch ^ grow) << 3);

  const ushort* rdA[2], * rdB[2];
#pragma unroll
  for (int kk = 0; kk < 2; ++kk) {
    rdA[kk] = SS + wm * (BM / 2) * 64 + lq * 64 + ((((kk << 2) | g) ^ (lq & 7)) << 3);
    rdB[kk] = SS + 2 * BM * 64 + wn * 4096 + lq * 64 + ((((kk << 2) | g) ^ (lq & 7)) << 3);
  }

  for (int kt = 0; kt < 768 / 64; ++kt) {
    __syncthreads();
#pragma unroll
    for (int i = 0; i < 16; ++i)
      if (i < ninst) gload16(gsrc + (size_t)i * (8 * 768) + kt * 64, lbase + i * 512);
    __syncthreads();
#pragma unroll
    for (int kk = 0; kk < 2; ++kk) {
      s16x8 ah[MF], al4[MF];
#pragma unroll
      for (int mf = 0; mf < MF; ++mf) {
        ah[mf]  = *(const s16x8*)(rdA[kk] + mf * 1024);
        al4[mf] = *(const s16x8*)(rdA[kk] + mf * 1024 + BM * 64);
      }
      __builtin_amdgcn_s_setprio(1);
#pragma unroll
      for (int nf = 0; nf < 4; ++nf) {
        const s16x8 bhf = *(const s16x8*)(rdB[kk] + nf * 1024);
        const s16x8 blf = *(const s16x8*)(rdB[kk] + nf * 1024 + 8192);
#pragma unroll
        for (int mf = 0; mf < MF; ++mf) {
          acc[mf][nf] = __builtin_amdgcn_mfma_f32_16x16x32_bf16(ah[mf], bhf, acc[mf][nf], 0, 0, 0);
          acc[mf][nf] = __builtin_amdgcn_mfma_f32_16x16x32_bf16(ah[mf], blf, acc[mf][nf], 0, 0, 0);
          acc[mf][nf] = __builtin_amdgcn_mfma_f32_16x16x32_bf16(al4[mf], bhf, acc[mf][nf], 0, 0, 0);
        }
      }
      __builtin_amdgcn_s_setprio(0);
    }
  }

  if constexpr (EPI == 0) {
    const int cidx = n0 / DMODEL;   // 0:q 1:k 2:v (block-uniform)
    if (cidx < 2) {
      ushort* dh = (cidx == 0) ? qh : kh;
      const float scl = (cidx == 0) ? QSCL : 1.0f;
#pragma unroll
      for (int nf = 0; nf < 4; ++nf) {
        const int n = n0 + wn * 64 + nf * 16 + lq;
        const int rem = n - cidx * DMODEL;
        const int hh = rem >> 6, d = rem & 63;
        const float sgn = (d & 1) ? 1.f : -1.f;
        const float bb = bias[n];
#pragma unroll
        for (int mf = 0; mf < MF; ++mf)
#pragma unroll
          for (int rg = 0; rg < 4; ++rg) {
            const int s = m0 + wm * (BM / 2) + mf * 16 + g * 4 + rg;
            const float v = acc[mf][nf][rg] + bb;
            const float vp = __shfl_xor(v, 1, 64);
            const float o = (v * ct[s * HD + d] + sgn * vp * st[s * HD + d]) * scl;
            const ushort hv = f2bf(o);
            const size_t off = (((size_t)hh * S_LEN + s) << 6) + d;
            dh[off] = hv;
            if (cidx == 0) ql[off] = f2bf(o - bf2f(hv));
          }
      }
    } else {
#pragma unroll
      for (int nf = 0; nf < 4; ++nf) {
        const int n = n0 + wn * 64 + nf * 16 + lq;
        const int rem = n - 2 * DMODEL;
        const int hh = rem >> 6, d = rem & 63;
        const float bb = bias[n];
#pragma unroll
        for (int mf = 0; mf < MF; ++mf) {
          union { ushort us[4]; ushort4 u4; } u;
#pragma unroll
          for (int rg = 0; rg < 4; ++rg) u.us[rg] = f2bf(acc[mf][nf][rg] + bb);
          const int sb = m0 + wm * (BM / 2) + mf * 16 + g * 4;
          *(ushort4*)(vt + ((size_t)hh * 64 + d) * S_LEN + sb) = u.u4;
        }
      }
    }
  } else {
#pragma unroll
    for (int nf = 0; nf < 4; ++nf) {
      const int n = n0 + wn * 64 + nf * 16 + lq;
      const float bb = bias[n];
#pragma unroll
      for (int mf = 0; mf < MF; ++mf)
#pragma unroll
        for (int rg = 0; rg < 4; ++rg) {
          const int s = m0 + wm * (BM / 2) + mf * 16 + g * 4 + rg;
          out[(size_t)s * DMODEL + n] = acc[mf][nf][rg] + bb;
        }
    }
  }
}

// ---------------- flash attention PARTIAL: R=32 q-rows/wave, K-split --------
// grid (S/128, 2, H), 256 threads = 4 waves; wave w owns 32 q-rows.
// Block (qb, khalf, h) processes k-tiles [khalf*32, khalf*32+32), emits
// unnormalized o + (m, l) partials; k_merge combines the two halves.
__global__ __launch_bounds__(256) void k_attn_part(
    const ushort* __restrict__ qh, const ushort* __restrict__ ql,
    const ushort* __restrict__ kh, const ushort* __restrict__ vt,
    float* __restrict__ po, float* __restrict__ ml) {
  const int h = blockIdx.z;
  const int khalf = blockIdx.y;
  const int s0 = blockIdx.x << 7;
  const int t = threadIdx.x;
  const int w = t >> 6, l = t & 63, lq = l & 15, g = l >> 4;

  __shared__ __align__(16) ushort Ks0[2 * 4096];  // [buf][64 k][64 d], swz
  __shared__ __align__(16) ushort Vs0[2 * 4096];  // [buf][64 d][64 k-perm], swz

  // Q B-fragments: u in {0,1} row-groups, hi/lo, two d-halves
  s16x8 qah[2][2], qal[2][2];
#pragma unroll
  for (int u = 0; u < 2; ++u) {
    const size_t qoff =
        ((size_t)h * S_LEN + s0 + (w << 5) + (u << 4) + lq) * 64 + (g << 3);
    qah[u][0] = *(const s16x8*)(qh + qoff);
    qah[u][1] = *(const s16x8*)(qh + qoff + 32);
    qal[u][0] = *(const s16x8*)(ql + qoff);
    qal[u][1] = *(const s16x8*)(ql + qoff + 32);
  }

  f32x4 o[2][4];
#pragma unroll
  for (int u = 0; u < 2; ++u)
#pragma unroll
    for (int m = 0; m < 4; ++m) o[u][m] = (f32x4){0.f, 0.f, 0.f, 0.f};
  float mrun[2] = {-3.0e30f, -3.0e30f};
  float lrun[2] = {0.f, 0.f};

  // loop-invariant LDS addresses
  const int b0 = (lq << 6) | ((g ^ (lq & 7)) << 3);
  const int b1 = (lq << 6) | (((g + 4) ^ (lq & 7)) << 3);
  const ushort* kr0 = Ks0 + b0;
  const ushort* kr1 = Ks0 + b1;
  const ushort* vr0 = Vs0 + b0;
  const ushort* vr1 = Vs0 + b1;
  const int r = t >> 2, c0 = (t & 3) << 1;
  const ushort* gk = kh + ((size_t)h * S_LEN + khalf * 2048 + r) * 64 + (c0 << 3);
  const ushort* gv = vt + ((size_t)h * 64 + r) * S_LEN + khalf * 2048 + (c0 << 3);
  ushort* kwp0 = Ks0 + ((r << 6) | ((c0 ^ (r & 7)) << 3));
  ushort* kwp1 = Ks0 + ((r << 6) | (((c0 + 1) ^ (r & 7)) << 3));
  ushort* vwp[2][2];
#pragma unroll
  for (int cc = 0; cc < 2; ++cc) {
    const int c = c0 + cc;
    const int k5 = c >> 2, k4 = (c >> 1) & 1, k3 = c & 1;
#pragma unroll
    for (int hh = 0; hh < 2; ++hh) {
      const int ch = 4 * k5 + 2 * k3 + hh;      // permuted chunk
      vwp[cc][hh] = Vs0 + ((r << 6) | ((ch ^ (r & 7)) << 3) | (k4 << 2));
    }
  }

  float4 sk0, sk1, sv0, sv1;
  auto ldg = [&]() {
    sk0 = *(const float4*)(gk); sk1 = *(const float4*)(gk + 8);
    sv0 = *(const float4*)(gv); sv1 = *(const float4*)(gv + 8);
    gk += 4096; gv += 64;
  };
  auto ldsw = [&](const int B) {
    *(float4*)(kwp0 + B * 4096) = sk0;
    *(float4*)(kwp1 + B * 4096) = sk1;
    union { float4 f; ushort4 h4[2]; } va, vb;
    va.f = sv0; vb.f = sv1;
    *(ushort4*)(vwp[0][0] + B * 4096) = va.h4[0];
    *(ushort4*)(vwp[0][1] + B * 4096) = va.h4[1];
    *(ushort4*)(vwp[1][0] + B * 4096) = vb.h4[0];
    *(ushort4*)(vwp[1][1] + B * 4096) = vb.h4[1];
  };

  ldg();
  ldsw(0);
  __syncthreads();

  auto body = [&](const int CUR, const int NX, const bool pref) {
    if (pref) ldg();
    // ---- QK^T swapped, both row-groups share the K fragments ----
    f32x4 sc[2][4];
    __builtin_amdgcn_s_setprio(1);
#pragma unroll
    for (int n = 0; n < 4; ++n) {
      const s16x8 ka0 = *(const s16x8*)(kr0 + CUR * 4096 + (n << 10));
      const s16x8 ka1 = *(const s16x8*)(kr1 + CUR * 4096 + (n << 10));
#pragma unroll
      for (int u = 0; u < 2; ++u) {
        f32x4 a = {0.f, 0.f, 0.f, 0.f};
        a = __builtin_amdgcn_mfma_f32_16x16x32_bf16(ka0, qah[u][0], a, 0, 0, 0);
        a = __builtin_amdgcn_mfma_f32_16x16x32_bf16(ka1, qah[u][1], a, 0, 0, 0);
        a = __builtin_amdgcn_mfma_f32_16x16x32_bf16(ka0, qal[u][0], a, 0, 0, 0);
        a = __builtin_amdgcn_mfma_f32_16x16x32_bf16(ka1, qal[u][1], a, 0, 0, 0);
        sc[u][n] = a;
      }
    }
    __builtin_amdgcn_s_setprio(0);

    // ---- online softmax with defer-max (per row-group state) ----
    float pm[2];
#pragma unroll
    for (int u = 0; u < 2; ++u) {
      float p = sc[u][0][0];
#pragma unroll
      for (int n = 0; n < 4; ++n)
#pragma unroll
        for (int rg = 0; rg < 4; ++rg) p = fmaxf(p, sc[u][n][rg]);
      pm[u] = p;
    }
    if (!__all((pm[0] - mrun[0] <= DEFER_THR) &&
               (pm[1] - mrun[1] <= DEFER_THR))) {
#pragma unroll
      for (int u = 0; u < 2; ++u) {
        float p = pm[u];
        p = fmaxf(p, __shfl_xor(p, 16, 64));
        p = fmaxf(p, __shfl_xor(p, 32, 64));
        const float mn = fmaxf(mrun[u], p);
        const float corr = exp2f(mrun[u] - mn);
        mrun[u] = mn;
        lrun[u] *= corr;
#pragma unroll
        for (int m = 0; m < 4; ++m) o[u][m] *= corr;
      }
    }
    union Pf { uint32_t uw[4]; s16x8 v; };
    Pf pu[2][2];
#pragma unroll
    for (int u = 0; u < 2; ++u) {
      float pr[4][4];
      float rs = 0.f;
#pragma unroll
      for (int n = 0; n < 4; ++n)
#pragma unroll
        for (int rg = 0; rg < 4; ++rg) {
          pr[n][rg] = exp2f(sc[u][n][rg] - mrun[u]);
          rs += pr[n][rg];
        }
      lrun[u] += rs;
      uint32_t uu[8];
#pragma unroll
      for (int n = 0; n < 4; ++n) {
        asm("v_cvt_pk_bf16_f32 %0, %1, %2"
            : "=v"(uu[2 * n]) : "v"(pr[n][0]), "v"(pr[n][1]));
        asm("v_cvt_pk_bf16_f32 %0, %1, %2"
            : "=v"(uu[2 * n + 1]) : "v"(pr[n][2]), "v"(pr[n][3]));
      }
      pu[u][0].uw[0] = uu[0]; pu[u][0].uw[1] = uu[1];
      pu[u][0].uw[2] = uu[2]; pu[u][0].uw[3] = uu[3];
      pu[u][1].uw[0] = uu[4]; pu[u][1].uw[1] = uu[5];
      pu[u][1].uw[2] = uu[6]; pu[u][1].uw[3] = uu[7];
    }

    // ---- PV swapped, V fragments shared across row-groups ----
    __builtin_amdgcn_s_setprio(1);
#pragma unroll
    for (int m = 0; m < 4; ++m) {
      const s16x8 va0 = *(const s16x8*)(vr0 + CUR * 4096 + (m << 10));
      const s16x8 va1 = *(const s16x8*)(vr1 + CUR * 4096 + (m << 10));
#pragma unroll
      for (int u = 0; u < 2; ++u) {
        o[u][m] = __builtin_amdgcn_mfma_f32_16x16x32_bf16(va0, pu[u][0].v, o[u][m], 0, 0, 0);
        o[u][m] = __builtin_amdgcn_mfma_f32_16x16x32_bf16(va1, pu[u][1].v, o[u][m], 0, 0, 0);
      }
    }
    __builtin_amdgcn_s_setprio(0);

    if (pref) ldsw(NX);
    __syncthreads();
  };

  for (int p = 0; p < 16; ++p) {
    body(0, 1, true);         // tile 2p   (prefetch 2p+1 -> buf1)
    body(1, 0, p < 15);       // tile 2p+1 (prefetch 2p+2 -> buf0)
  }

  // epilogue: reduce l across groups, write unnormalized partials + (m,l)
#pragma unroll
  for (int u = 0; u < 2; ++u) {
    float lr = lrun[u];
    lr += __shfl_xor(lr, 16, 64);
    lr += __shfl_xor(lr, 32, 64);
    const int q = s0 + (w << 5) + (u << 4) + lq;
    const size_t rb = (((size_t)h * S_LEN + q) * 2 + khalf) * 64;
#pragma unroll
    for (int m = 0; m < 4; ++m) {
      float4 res;
      res.x = o[u][m][0]; res.y = o[u][m][1];
      res.z = o[u][m][2]; res.w = o[u][m][3];
      *(float4*)(po + rb + (m << 4) + (g << 2)) = res;
    }
    if (g == 0)
      ((float2*)ml)[((size_t)h * S_LEN + q) * 2 + khalf] = make_float2(mrun[u], lr);
  }
}

// ---------------- merge the two K-halves, write ctx as bf16 hi/lo -----------
__global__ __launch_bounds__(256) void k_merge(
    const float* __restrict__ po, const float* __restrict__ ml,
    ushort* __restrict__ cxh, ushort* __restrict__ cxl) {
  const int t = threadIdx.x;
  const int row = blockIdx.x * 16 + (t >> 4);   // h*S + s
  const int c = t & 15;
  const int h = row >> 12, s = row & 4095;
  const float2 a = ((const float2*)ml)[(size_t)row * 2 + 0];
  const float2 b = ((const float2*)ml)[(size_t)row * 2 + 1];
  const float m = fmaxf(a.x, b.x);
  const float wa = exp2f(a.x - m), wb = exp2f(b.x - m);
  const float inv = 1.0f / (a.y * wa + b.y * wb);
  const float4 oa = *(const float4*)(po + (size_t)row * 128 + (c << 2));
  const float4 ob = *(const float4*)(po + (size_t)row * 128 + 64 + (c << 2));
  const float v0 = (oa.x * wa + ob.x * wb) * inv;
  const float v1 = (oa.y * wa + ob.y * wb) * inv;
  const float v2 = (oa.z * wa + ob.z * wb) * inv;
  const float v3 = (oa.w * wa + ob.w * wb) * inv;
  uint32_t h01, h23;
  asm("v_cvt_pk_bf16_f32 %0, %1, %2" : "=v"(h01) : "v"(v0), "v"(v1));
  asm("v_cvt_pk_bf16_f32 %0, %1, %2" : "=v"(h23) : "v"(v2), "v"(v3));
  const float r0 = __uint_as_float(h01 << 16);
  const float r1 = __uint_as_float(h01 & 0xffff0000u);
  const float r2 = __uint_as_float(h23 << 16);
  const float r3 = __uint_as_float(h23 & 0xffff0000u);
  uint32_t l01, l23;
  asm("v_cvt_pk_bf16_f32 %0, %1, %2" : "=v"(l01) : "v"(v0 - r0), "v"(v1 - r1));
  asm("v_cvt_pk_bf16_f32 %0, %1, %2" : "=v"(l23) : "v"(v2 - r2), "v"(v3 - r3));
  const size_t off = (size_t)s * DMODEL + (h << 6) + (c << 2);
  uint2 hq, lqv;
  hq.x = h01; hq.y = h23; lqv.x = l01; lqv.y = l23;
  *(uint2*)(cxh + off) = hq;
  *(uint2*)(cxl + off) = lqv;
}

extern "C" void kernel_launch(void* const* d_in, const int* in_sizes, int n_in,
                              void* d_out, int out_size, void* d_ws, size_t ws_size,
                              hipStream_t stream) {
  const float* x    = (const float*)d_in[0];
  const float* Wqkv = (const float*)d_in[1];
  const float* bqkv = (const float*)d_in[2];
  const float* Wout = (const float*)d_in[3];
  const float* bout = (const float*)d_in[4];
  float* out = (float*)d_out;

  const size_t NQ = (size_t)NH * S_LEN * HD;   // 3,145,728
  const size_t ND = (size_t)S_LEN * DMODEL;    // 3,145,728
  char* base = (char*)d_ws;
  ushort* qh = (ushort*)base;
  ushort* ql = qh + NQ;
  ushort* kh = ql + NQ;
  ushort* vt = kh + NQ;
  ushort* xh = vt + NQ;          // [S][768] hi; reused as cxh after qkv GEMM
  ushort* xl = xh + ND;          // lo; reused as cxl
  float* ct = (float*)(xl + ND);
  float* st = ct + (size_t)S_LEN * HD;
  ushort* Wth = (ushort*)(st + (size_t)S_LEN * HD);    // [2304][768]
  ushort* Wtl = Wth + (size_t)3 * DMODEL * DMODEL;
  ushort* Woth = Wtl + (size_t)3 * DMODEL * DMODEL;    // [768][768]
  ushort* Wotl = Woth + (size_t)DMODEL * DMODEL;
  float* po = (float*)(Wotl + (size_t)DMODEL * DMODEL);  // [H][S][2][64] f32
  float* ml = po + (size_t)NH * S_LEN * 128;             // [H][S][2] float2

  k_build_trig<<<dim3(S_LEN), dim3(64), 0, stream>>>(ct, st);
  k_tsplit<<<dim3(3 * DMODEL / 32, DMODEL / 32), dim3(256), 0, stream>>>(
      Wqkv, Wth, Wtl, DMODEL, 3 * DMODEL);
  k_tsplit<<<dim3(DMODEL / 32, DMODEL / 32), dim3(256), 0, stream>>>(
      Wout, Woth, Wotl, DMODEL, DMODEL);
  k_splitf<<<dim3((int)(ND / 4 / 256)), dim3(256), 0, stream>>>(
      x, xh, xl, (int)(ND / 4));
  k_gemm_split<0, 128><<<dim3(3 * DMODEL / 128, S_LEN / 128), dim3(256), 0, stream>>>(
      xh, xl, Wth, Wtl, bqkv, ct, st, qh, ql, kh, vt, nullptr);
  k_attn_part<<<dim3(S_LEN / 128, 2, NH), dim3(256), 0, stream>>>(
      qh, ql, kh, vt, po, ml);
  k_merge<<<dim3(NH * S_LEN / 16), dim3(256), 0, stream>>>(po, ml, xh, xl);
  k_gemm_split<1, 64><<<dim3(DMODEL / 128, S_LEN / 64), dim3(256), 0, stream>>>(
      xh, xl, Woth, Wotl, bout, nullptr, nullptr,
      nullptr, nullptr, nullptr, nullptr, out);
}